// Round 10
// baseline (444.715 us; speedup 1.0000x reference)
//
#include <hip/hip_runtime.h>

// ---------------------------------------------------------------------------
// 3-layer GCN: out = ReLU(Â(ReLU(Â(Â (X W1^T) +b1) W2^T +b2)) W3^T) +b3
// Â = D^{-1/2}(A+I)D^{-1/2}, deg = in-degree + 1 (self loop).
//
// R21: dispatch-level overlap. R18-R20 pm: five GEMM structures all ~45us
// with every pipe <16% while static floors say ~10us -> the cost is chain
// serialization, not in-kernel work. GEMM1's only preprocess dependency is
// dinv; hoist it via a degree histogram (== build_buckets' myc, CAP
// overflow is 9-sigma -> bit-identical), then co-dispatch GEMM1 with the
// preprocess: fused1 = {bin_edges || gemm1 tiles[0,T1)}, fused2 =
// {build_buckets || gemm1 tiles[T1,nt)}. LDS overlaid via char buffer.
// GEMM2/3 reverted to R17-exact merged-chunk (best measured total).
// ---------------------------------------------------------------------------

#define NPB 256          // nodes per bucket (bucket = dst >> 8)
#define CAP 4672         // edges capacity per bucket region
#define BIN_WGS 512      // workgroups in bin_edges
#define LDP 136          // padded LDS row stride (bf16)

typedef short bfrag __attribute__((ext_vector_type(8)));       // 8 bf16
typedef float f32x4 __attribute__((ext_vector_type(4)));
typedef unsigned short u16x8 __attribute__((ext_vector_type(8)));

// ---------------------------------------------------------------------------
__device__ inline unsigned short bf16rne(float x) {
  unsigned u = __float_as_uint(x);
  return (unsigned short)((u + 0x7FFFu + ((u >> 16) & 1u)) >> 16);
}
__device__ inline float bf16lo(unsigned q) { return __uint_as_float(q << 16); }
__device__ inline float bf16hi(unsigned q) { return __uint_as_float(q & 0xFFFF0000u); }

// ---------------------------------------------------------------------------
// Kernel A: W hi/lo splits + cur init + degree histogram (extra blocks).
// deg must be zeroed (hipMemsetAsync) before this kernel.
// ---------------------------------------------------------------------------
__global__ __launch_bounds__(256) void split_w3_deg(const float* __restrict__ W1,
                                                    const float* __restrict__ W2,
                                                    const float* __restrict__ W3,
                                                    unsigned short* __restrict__ w1h,
                                                    unsigned short* __restrict__ w1l,
                                                    unsigned short* __restrict__ w2h,
                                                    unsigned short* __restrict__ w2l,
                                                    unsigned short* __restrict__ w3h,
                                                    unsigned short* __restrict__ w3l,
                                                    int* __restrict__ cur,
                                                    int* __restrict__ deg,
                                                    const int* __restrict__ dst,
                                                    int B, int E, int NS) {
  const int bid = blockIdx.x;
  const int t = threadIdx.x;
  if (bid >= NS) {  // degree-histogram blocks
    const int hb = bid - NS;
    const int chunk = (E + BIN_WGS - 1) / BIN_WGS;
    const int e0 = hb * chunk;
    const int e1 = min(E, e0 + chunk);
    for (int e = e0 + t; e < e1; e += 256)
      atomicAdd(&deg[__builtin_nontemporal_load(&dst[e])], 1);
    return;
  }
  int i = bid * 256 + t;
  const float* W;
  unsigned short *hi, *lo;
  int j;
  if (i < 16384) {
    W = W1; hi = w1h; lo = w1l; j = i;
  } else if (i < 32768) {
    W = W2; hi = w2h; lo = w2l; j = i - 16384;
  } else if (i < 40960) {
    W = W3; hi = w3h; lo = w3l; j = i - 32768;
  } else if (i < 40960 + B) {
    cur[i - 40960] = (i - 40960) * CAP;
    return;
  } else {
    return;
  }
  float v = W[j];
  unsigned short h = bf16rne(v);
  hi[j] = h;
  lo[j] = bf16rne(v - __uint_as_float((unsigned)h << 16));
}

__global__ __launch_bounds__(256) void dinv_k(const int* __restrict__ deg,
                                              float* __restrict__ dinv, int N) {
  int i = blockIdx.x * 256 + threadIdx.x;
  if (i < N) dinv[i] = rsqrtf((float)(deg[i] + 1));
}

// ---------------------------------------------------------------------------
// Device bodies for the fused dispatches.
// ---------------------------------------------------------------------------
__device__ inline void bin_edges_body(char* smem,
                                      const int* __restrict__ src,
                                      const int* __restrict__ dst,
                                      int* __restrict__ cur,
                                      int* __restrict__ binned,
                                      int E, int B) {
  int* lc = (int*)smem;           // 512 ints
  int* lbase = lc + 512;          // 512 ints
  const int t = threadIdx.x;
  const int chunk = (E + BIN_WGS - 1) / BIN_WGS;
  const int e0 = blockIdx.x * chunk;
  const int e1 = min(E, e0 + chunk);

  for (int i = t; i < B; i += 256) lc[i] = 0;
  __syncthreads();
  for (int e = e0 + t; e < e1; e += 256) {
    int d = dst[e];
    atomicAdd(&lc[d >> 8], 1);
  }
  __syncthreads();
  for (int i = t; i < B; i += 256) {
    int c = lc[i];
    lbase[i] = c ? atomicAdd(&cur[i], c) : 0;
    lc[i] = 0;
  }
  __syncthreads();
  for (int e = e0 + t; e < e1; e += 256) {
    int d = dst[e];
    int s = __builtin_nontemporal_load(&src[e]);
    int bk = d >> 8;
    int p = lbase[bk] + atomicAdd(&lc[bk], 1);
    if (p < (bk + 1) * CAP)
      binned[p] = ((d & 255) << 24) | s;
  }
}

__device__ inline void build_buckets_body(char* smem, int b,
                                          const int* __restrict__ binned,
                                          const int* __restrict__ cur,
                                          int* __restrict__ cols,
                                          int2* __restrict__ off2,
                                          int N) {
  int* eb = (int*)smem;            // CAP
  int* ob = eb + CAP;              // CAP
  int* lc = ob + CAP;              // 256
  int* sc = lc + 256;              // 256
  const int t = threadIdx.x;
  const int base = b * CAP;
  const int cntb = min(cur[b] - base, CAP);

  for (int i = t; i < cntb; i += 256) eb[i] = binned[base + i];
  lc[t] = 0;
  __syncthreads();
  for (int i = t; i < cntb; i += 256)
    atomicAdd(&lc[(unsigned)eb[i] >> 24], 1);
  __syncthreads();
  int myc = lc[t];
  sc[t] = myc;
  __syncthreads();
  for (int d = 1; d < 256; d <<= 1) {
    int a = (t >= d) ? sc[t - d] : 0;
    __syncthreads();
    sc[t] += a;
    __syncthreads();
  }
  int excl = sc[t] - myc;
  int node = b * NPB + t;
  if (node < N)
    off2[node] = make_int2(base + excl, base + excl + myc);
  lc[t] = excl;
  __syncthreads();
  for (int i = t; i < cntb; i += 256) {
    int e = eb[i];
    int p = atomicAdd(&lc[(unsigned)e >> 24], 1);
    ob[p] = e & 0xFFFFFF;
  }
  __syncthreads();
  for (int i = t; i < cntb; i += 256) cols[base + i] = ob[i];
}

// R17-exact layer-1 GEMM body (OUTC=128, CSOUT): A from f32 X split in-reg.
__device__ inline void gemm_xsplit_body(char* smem, int mtile,
                                        const float* __restrict__ X,
                                        const unsigned short* __restrict__ Whg,
                                        const unsigned short* __restrict__ Wlg,
                                        const float* __restrict__ dinv,
                                        unsigned short* __restrict__ Y,
                                        int M) {
  unsigned short* Whi = (unsigned short*)smem;         // 64*LDP
  unsigned short* Wlo = Whi + 64 * LDP;                // 64*LDP
  const int tid = threadIdx.x;
  const int m_base = mtile * 64;
  const int lane = tid & 63;
  const int wv = tid >> 6;
  const int col_l = lane & 15;
  const int quad = lane >> 4;
  const size_t arow = (size_t)min(m_base + wv * 16 + col_l, M - 1) * 128;
  const int bBase = col_l * LDP + quad * 8;

  bfrag aH[4], aL[4];
#pragma unroll
  for (int ks = 0; ks < 4; ++ks) {
    float4 v0 = *(const float4*)(X + arow + ks * 32 + quad * 8);
    float4 v1 = *(const float4*)(X + arow + ks * 32 + quad * 8 + 4);
    float vv[8] = {v0.x, v0.y, v0.z, v0.w, v1.x, v1.y, v1.z, v1.w};
#pragma unroll
    for (int j = 0; j < 8; ++j) {
      unsigned short h = bf16rne(vv[j]);
      aH[ks][j] = (short)h;
      aL[ks][j] = (short)bf16rne(vv[j] - __uint_as_float((unsigned)h << 16));
    }
  }

  f32x4 acc[2][4];
#pragma unroll
  for (int c2 = 0; c2 < 2; ++c2)
#pragma unroll
    for (int t = 0; t < 4; ++t) acc[c2][t] = {0.f, 0.f, 0.f, 0.f};

#pragma unroll
  for (int c2 = 0; c2 < 2; ++c2) {
    if (c2) __syncthreads();
    for (int idx = tid; idx < 64 * 16; idx += 256) {
      int r = idx >> 4, g = idx & 15;
      *(u16x8*)(Whi + r * LDP + g * 8) =
          *(const u16x8*)(Whg + (size_t)(c2 * 64 + r) * 128 + g * 8);
      *(u16x8*)(Wlo + r * LDP + g * 8) =
          *(const u16x8*)(Wlg + (size_t)(c2 * 64 + r) * 128 + g * 8);
    }
    __syncthreads();
#pragma unroll
    for (int ks = 0; ks < 4; ++ks) {
#pragma unroll
      for (int t = 0; t < 4; ++t) {
        int bo = bBase + t * 16 * LDP + ks * 32;
        bfrag bHi = *(const bfrag*)(Whi + bo);
        bfrag bLo = *(const bfrag*)(Wlo + bo);
        acc[c2][t] = __builtin_amdgcn_mfma_f32_16x16x32_bf16(aH[ks], bHi, acc[c2][t], 0, 0, 0);
        acc[c2][t] = __builtin_amdgcn_mfma_f32_16x16x32_bf16(aL[ks], bHi, acc[c2][t], 0, 0, 0);
        acc[c2][t] = __builtin_amdgcn_mfma_f32_16x16x32_bf16(aH[ks], bLo, acc[c2][t], 0, 0, 0);
      }
    }
  }

#pragma unroll
  for (int r = 0; r < 4; ++r) {
    int row = m_base + wv * 16 + quad * 4 + r;
    if (row < M) {
      float s = dinv[row];
#pragma unroll
      for (int c2 = 0; c2 < 2; ++c2)
#pragma unroll
        for (int t = 0; t < 4; ++t) {
          unsigned short h = bf16rne(acc[c2][t][r] * s);
          Y[((size_t)c2 * M + row) * 64 + t * 16 + col_l] = h;
        }
    }
  }
}

// ---------------------------------------------------------------------------
// Fused dispatches: preprocess blocks || GEMM1 tile blocks.
// ---------------------------------------------------------------------------
__global__ __launch_bounds__(256) void fused_bin_gemm(const int* __restrict__ src,
                                                      const int* __restrict__ dst,
                                                      int* __restrict__ cur,
                                                      int* __restrict__ binned,
                                                      int E, int B,
                                                      const float* __restrict__ X,
                                                      const unsigned short* __restrict__ Whg,
                                                      const unsigned short* __restrict__ Wlg,
                                                      const float* __restrict__ dinv,
                                                      unsigned short* __restrict__ Y,
                                                      int M) {
  __shared__ __align__(16) char smem[34816];
  if (blockIdx.x < BIN_WGS)
    bin_edges_body(smem, src, dst, cur, binned, E, B);
  else
    gemm_xsplit_body(smem, blockIdx.x - BIN_WGS, X, Whg, Wlg, dinv, Y, M);
}

__global__ __launch_bounds__(256) void fused_bb_gemm(const int* __restrict__ binned,
                                                     const int* __restrict__ cur,
                                                     int* __restrict__ cols,
                                                     int2* __restrict__ off2,
                                                     int N, int B,
                                                     const float* __restrict__ X,
                                                     const unsigned short* __restrict__ Whg,
                                                     const unsigned short* __restrict__ Wlg,
                                                     const float* __restrict__ dinv,
                                                     unsigned short* __restrict__ Y,
                                                     int T1) {
  __shared__ __align__(16) char smem[39424];
  if ((int)blockIdx.x < B)
    build_buckets_body(smem, blockIdx.x, binned, cur, cols, off2, N);
  else
    gemm_xsplit_body(smem, T1 + blockIdx.x - B, X, Whg, Wlg, dinv, Y, N);
}

// ---------------------------------------------------------------------------
// GEMM (R17-exact): layer 2/3, A from bf16 hi/lo planes in global.
// ---------------------------------------------------------------------------
template <int OUTC, bool CSOUT>
__global__ __launch_bounds__(256) void gemm_planes(const unsigned short* __restrict__ Xh,
                                                   const unsigned short* __restrict__ Xl,
                                                   const unsigned short* __restrict__ Whg,
                                                   const unsigned short* __restrict__ Wlg,
                                                   const float* __restrict__ dinv,
                                                   unsigned short* __restrict__ Y,
                                                   int M) {
  constexpr int CHUNKS = OUTC / 64;
  __shared__ unsigned short Whi[64 * LDP], Wlo[64 * LDP];
  const int tid = threadIdx.x;
  const int m_base = blockIdx.x * 64;
  const int lane = tid & 63;
  const int wv = tid >> 6;
  const int col_l = lane & 15;
  const int quad = lane >> 4;
  const size_t arow = (size_t)min(m_base + wv * 16 + col_l, M - 1) * 128;
  const int bBase = col_l * LDP + quad * 8;

  bfrag aH[4], aL[4];
#pragma unroll
  for (int ks = 0; ks < 4; ++ks) {
    aH[ks] = *(const bfrag*)(Xh + arow + ks * 32 + quad * 8);
    aL[ks] = *(const bfrag*)(Xl + arow + ks * 32 + quad * 8);
  }

  f32x4 acc[CHUNKS][4];
#pragma unroll
  for (int c2 = 0; c2 < CHUNKS; ++c2)
#pragma unroll
    for (int t = 0; t < 4; ++t) acc[c2][t] = {0.f, 0.f, 0.f, 0.f};

#pragma unroll
  for (int c2 = 0; c2 < CHUNKS; ++c2) {
    if (c2) __syncthreads();
    for (int idx = tid; idx < 64 * 16; idx += 256) {
      int r = idx >> 4, g = idx & 15;
      *(u16x8*)(Whi + r * LDP + g * 8) =
          *(const u16x8*)(Whg + (size_t)(c2 * 64 + r) * 128 + g * 8);
      *(u16x8*)(Wlo + r * LDP + g * 8) =
          *(const u16x8*)(Wlg + (size_t)(c2 * 64 + r) * 128 + g * 8);
    }
    __syncthreads();
#pragma unroll
    for (int ks = 0; ks < 4; ++ks) {
#pragma unroll
      for (int t = 0; t < 4; ++t) {
        int bo = bBase + t * 16 * LDP + ks * 32;
        bfrag bHi = *(const bfrag*)(Whi + bo);
        bfrag bLo = *(const bfrag*)(Wlo + bo);
        acc[c2][t] = __builtin_amdgcn_mfma_f32_16x16x32_bf16(aH[ks], bHi, acc[c2][t], 0, 0, 0);
        acc[c2][t] = __builtin_amdgcn_mfma_f32_16x16x32_bf16(aL[ks], bHi, acc[c2][t], 0, 0, 0);
        acc[c2][t] = __builtin_amdgcn_mfma_f32_16x16x32_bf16(aH[ks], bLo, acc[c2][t], 0, 0, 0);
      }
    }
  }

#pragma unroll
  for (int r = 0; r < 4; ++r) {
    int row = m_base + wv * 16 + quad * 4 + r;
    if (row < M) {
      float s = dinv[row];
#pragma unroll
      for (int c2 = 0; c2 < CHUNKS; ++c2)
#pragma unroll
        for (int t = 0; t < 4; ++t) {
          unsigned short h = bf16rne(acc[c2][t][r] * s);
          if (CSOUT)
            Y[((size_t)c2 * M + row) * 64 + t * 16 + col_l] = h;
          else
            Y[(size_t)row * OUTC + c2 * 64 + t * 16 + col_l] = h;
        }
    }
  }
}

__device__ inline void acc_add(float* a, uint4 d) {
  a[0] += bf16lo(d.x); a[1] += bf16hi(d.x);
  a[2] += bf16lo(d.y); a[3] += bf16hi(d.y);
  a[4] += bf16lo(d.z); a[5] += bf16hi(d.z);
  a[6] += bf16lo(d.w); a[7] += bf16hi(d.w);
}

// ---------------------------------------------------------------------------
// Aggregate v8 (C=128, cg=2 half-row split, R17-exact).
// ---------------------------------------------------------------------------
__global__ __launch_bounds__(256) void aggregate_h2(const unsigned short* __restrict__ xs,
                                                    const int2* __restrict__ off2,
                                                    const int* __restrict__ cols,
                                                    const float* __restrict__ dinv,
                                                    const float* __restrict__ bias,
                                                    unsigned short* __restrict__ oh,
                                                    unsigned short* __restrict__ ol,
                                                    int N) {
  const int cg = blockIdx.x & 1;        // half-row group; fixed per XCD parity
  const int tile = blockIdx.x >> 1;
  const int t = threadIdx.x;
  const int gl = t & 7;                 // lane within node (8 x 16B = 128B)
  const int node = tile * 32 + (t >> 3);
  if (node >= N) return;

  const char* xb = (const char*)xs + (size_t)cg * N * 128;  // contiguous slice
  const unsigned go = (unsigned)gl * 16;

  float acc[8];
  {
    uint4 d = *(const uint4*)(xb + (size_t)node * 128 + go);
    acc[0] = bf16lo(d.x); acc[1] = bf16hi(d.x);
    acc[2] = bf16lo(d.y); acc[3] = bf16hi(d.y);
    acc[4] = bf16lo(d.z); acc[5] = bf16hi(d.z);
    acc[6] = bf16lo(d.w); acc[7] = bf16hi(d.w);
  }

  const int2 oo = off2[node];
  const int en = oo.y;
  for (int e0 = oo.x; e0 < en; e0 += 8) {
    int col = __builtin_nontemporal_load(&cols[min(e0 + gl, en - 1)]);
    int m = en - e0;
    if (m > 8) m = 8;
    const int c1 = m - 1;
    for (int j = 0; j < m; j += 4) {
      int s0 = __shfl(col, min(j,     c1), 8);
      int s1 = __shfl(col, min(j + 1, c1), 8);
      int s2 = __shfl(col, min(j + 2, c1), 8);
      int s3 = __shfl(col, min(j + 3, c1), 8);
      uint4 d0 = *(const uint4*)(xb + (size_t)s0 * 128 + go);
      uint4 d1 = *(const uint4*)(xb + (size_t)s1 * 128 + go);
      uint4 d2 = *(const uint4*)(xb + (size_t)s2 * 128 + go);
      uint4 d3 = *(const uint4*)(xb + (size_t)s3 * 128 + go);
      acc_add(acc, d0);                       // j < m always
      if (j + 1 < m) acc_add(acc, d1);
      if (j + 2 < m) acc_add(acc, d2);
      if (j + 3 < m) acc_add(acc, d3);
    }
  }

  const float dd = dinv[node];
  const float4 bA = *(const float4*)(bias + cg * 64 + gl * 8);
  const float4 bB = *(const float4*)(bias + cg * 64 + gl * 8 + 4);
  float h[8];
  h[0] = acc[0] * dd + bA.x; h[1] = acc[1] * dd + bA.y;
  h[2] = acc[2] * dd + bA.z; h[3] = acc[3] * dd + bA.w;
  h[4] = acc[4] * dd + bB.x; h[5] = acc[5] * dd + bB.y;
  h[6] = acc[6] * dd + bB.z; h[7] = acc[7] * dd + bB.w;
#pragma unroll
  for (int q = 0; q < 8; ++q) h[q] = fmaxf(h[q], 0.f);

  u16x8 hv, lv;
#pragma unroll
  for (int q = 0; q < 8; ++q) {
    unsigned short hb = bf16rne(h[q]);
    hv[q] = hb;
    lv[q] = bf16rne(h[q] - __uint_as_float((unsigned)hb << 16));
  }
  const size_t ob = (size_t)node * 128 + cg * 64 + gl * 8;
  __builtin_nontemporal_store(hv, (u16x8*)(oh + ob));
  __builtin_nontemporal_store(lv, (u16x8*)(ol + ob));
}

// ---------------------------------------------------------------------------
// Aggregate v4 (C=64 final layer; standard [N][64] xs layout).
// ---------------------------------------------------------------------------
template <int C, bool RELU, bool SPLIT>
__global__ __launch_bounds__(256) void aggregate4(const unsigned short* __restrict__ xs,
                                                  const int2* __restrict__ off2,
                                                  const int* __restrict__ cols,
                                                  const float* __restrict__ dinv,
                                                  const float* __restrict__ bias,
                                                  float* __restrict__ outf,
                                                  unsigned short* __restrict__ oh,
                                                  unsigned short* __restrict__ ol,
                                                  int N) {
  constexpr int GL = C / 8;            // lanes per node
  constexpr int LSH = (GL == 16) ? 4 : 3;
  constexpr int NPBk = 256 / GL;       // nodes per block
  const int t = threadIdx.x;
  const int gl = t & (GL - 1);
  const int node = blockIdx.x * NPBk + (t >> LSH);
  if (node >= N) return;

  const unsigned co = (unsigned)gl * 16;  // byte offset of this lane's 8 ch
  const char* xb = (const char*)xs;

  float acc[8];
  {
    uint4 d = *(const uint4*)(xb + (size_t)node * (C * 2) + co);
    acc[0] = bf16lo(d.x); acc[1] = bf16hi(d.x);
    acc[2] = bf16lo(d.y); acc[3] = bf16hi(d.y);
    acc[4] = bf16lo(d.z); acc[5] = bf16hi(d.z);
    acc[6] = bf16lo(d.w); acc[7] = bf16hi(d.w);
  }

  const int2 oo = off2[node];
  const int en = oo.y;
  for (int e0 = oo.x; e0 < en; e0 += GL) {
    int col = __builtin_nontemporal_load(&cols[min(e0 + gl, en - 1)]);
    int m = en - e0;
    if (m > GL) m = GL;
    const int c1 = m - 1;
    for (int j = 0; j < m; j += 4) {
      int s0 = __shfl(col, min(j,     c1), GL);
      int s1 = __shfl(col, min(j + 1, c1), GL);
      int s2 = __shfl(col, min(j + 2, c1), GL);
      int s3 = __shfl(col, min(j + 3, c1), GL);
      uint4 d0 = *(const uint4*)(xb + (size_t)s0 * (C * 2) + co);
      uint4 d1 = *(const uint4*)(xb + (size_t)s1 * (C * 2) + co);
      uint4 d2 = *(const uint4*)(xb + (size_t)s2 * (C * 2) + co);
      uint4 d3 = *(const uint4*)(xb + (size_t)s3 * (C * 2) + co);
      acc_add(acc, d0);                       // j < m always
      if (j + 1 < m) acc_add(acc, d1);
      if (j + 2 < m) acc_add(acc, d2);
      if (j + 3 < m) acc_add(acc, d3);
    }
  }

  const float dd = dinv[node];
  const float4 bA = *(const float4*)(bias + gl * 8);
  const float4 bB = *(const float4*)(bias + gl * 8 + 4);
  float h[8];
  h[0] = acc[0] * dd + bA.x; h[1] = acc[1] * dd + bA.y;
  h[2] = acc[2] * dd + bA.z; h[3] = acc[3] * dd + bA.w;
  h[4] = acc[4] * dd + bB.x; h[5] = acc[5] * dd + bB.y;
  h[6] = acc[6] * dd + bB.z; h[7] = acc[7] * dd + bB.w;
  if (RELU) {
#pragma unroll
    for (int q = 0; q < 8; ++q) h[q] = fmaxf(h[q], 0.f);
  }
  if (SPLIT) {
    u16x8 hv, lv;
#pragma unroll
    for (int q = 0; q < 8; ++q) {
      unsigned short hb = bf16rne(h[q]);
      hv[q] = hb;
      lv[q] = bf16rne(h[q] - __uint_as_float((unsigned)hb << 16));
    }
    __builtin_nontemporal_store(hv, (u16x8*)(oh + (size_t)node * C + gl * 8));
    __builtin_nontemporal_store(lv, (u16x8*)(ol + (size_t)node * C + gl * 8));
  } else {
    f32x4 oA = {h[0], h[1], h[2], h[3]};
    f32x4 oB = {h[4], h[5], h[6], h[7]};
    __builtin_nontemporal_store(oA, (f32x4*)(outf + (size_t)node * C + gl * 8));
    __builtin_nontemporal_store(oB, (f32x4*)(outf + (size_t)node * C + gl * 8 + 4));
  }
}

// ---------------------------------------------------------------------------

extern "C" void kernel_launch(void* const* d_in, const int* in_sizes, int n_in,
                              void* d_out, int out_size, void* d_ws, size_t ws_size,
                              hipStream_t stream) {
  const float* x  = (const float*)d_in[0];
  const int*   ei = (const int*)d_in[1];
  const float* W1 = (const float*)d_in[2];
  const float* b1 = (const float*)d_in[3];
  const float* W2 = (const float*)d_in[4];
  const float* b2 = (const float*)d_in[5];
  const float* W3 = (const float*)d_in[6];
  const float* b3 = (const float*)d_in[7];

  const int N = in_sizes[0] / 128;
  const int E = in_sizes[1] / 2;
  const int* src = ei;
  const int* dst = ei + E;
  const int B = (N + NPB - 1) / NPB;

  char* w = (char*)d_ws;
  size_t p = 0;
  auto alloc = [&](size_t bytes) -> void* {
    void* r = w + p;
    p = (p + bytes + 255) & ~(size_t)255;
    return r;
  };
  float*    dinv   = (float*)alloc((size_t)N * 4);
  int*      deg    = (int*)alloc((size_t)N * 4);
  int2*     off2   = (int2*)alloc((size_t)N * 8);
  int*      cur    = (int*)alloc((size_t)B * 4);
  int*      binned = (int*)alloc((size_t)B * CAP * 4);
  int*      cols   = (int*)alloc((size_t)B * CAP * 4);
  unsigned short* xsb = (unsigned short*)alloc((size_t)N * 128 * 2);  // GEMM out
  unsigned short* hh  = (unsigned short*)alloc((size_t)N * 128 * 2);  // h hi plane
  unsigned short* hl  = (unsigned short*)alloc((size_t)N * 128 * 2);  // h lo plane
  unsigned short* w1h = (unsigned short*)alloc(128 * 128 * 2);
  unsigned short* w1l = (unsigned short*)alloc(128 * 128 * 2);
  unsigned short* w2h = (unsigned short*)alloc(128 * 128 * 2);
  unsigned short* w2l = (unsigned short*)alloc(128 * 128 * 2);
  unsigned short* w3h = (unsigned short*)alloc(64 * 128 * 2);
  unsigned short* w3l = (unsigned short*)alloc(64 * 128 * 2);

  const int NS = (40960 + B + 255) / 256;   // split_w3 blocks
  const int ntiles = (N + 63) / 64;         // GEMM1 64-row m-tiles
  const int T1 = min(600, ntiles);          // tiles co-dispatched with bin_edges
  const int gb = (N + 63) / 64;
  const int T = (N + 31) / 32;              // h2 node tiles
  const int ab64 = (N + 31) / 32;

  hipMemsetAsync(deg, 0, (size_t)N * 4, stream);
  split_w3_deg<<<NS + BIN_WGS, 256, 0, stream>>>(W1, W2, W3, w1h, w1l, w2h, w2l,
                                                 w3h, w3l, cur, deg, dst, B, E, NS);
  dinv_k<<<(N + 255) / 256, 256, 0, stream>>>(deg, dinv, N);

  // {bin_edges || gemm1 tiles [0,T1)}
  fused_bin_gemm<<<BIN_WGS + T1, 256, 0, stream>>>(src, dst, cur, binned, E, B,
                                                   x, w1h, w1l, dinv, xsb, N);
  // {build_buckets || gemm1 tiles [T1,ntiles)}
  fused_bb_gemm<<<B + (ntiles - T1), 256, 0, stream>>>(binned, cur, cols, off2,
                                                       N, B, x, w1h, w1l, dinv,
                                                       xsb, T1);

  aggregate_h2<<<T * 2, 256, 0, stream>>>(xsb, off2, cols, dinv, b1, hh, hl, N);
  gemm_planes<128, true><<<gb, 256, 0, stream>>>(hh, hl, w2h, w2l, dinv, xsb, N);
  aggregate_h2<<<T * 2, 256, 0, stream>>>(xsb, off2, cols, dinv, b2, hh, hl, N);
  gemm_planes<64, false><<<gb, 256, 0, stream>>>(hh, hl, w3h, w3l, dinv, xsb, N);
  aggregate4<64, false, false><<<ab64, 256, 0, stream>>>(xsb, off2, cols, dinv, b3,
                                                         (float*)d_out, nullptr,
                                                         nullptr, N);
}

// Round 11
// 376.228 us; speedup vs baseline: 1.1820x; 1.1820x over previous
//
#include <hip/hip_runtime.h>

// ---------------------------------------------------------------------------
// 3-layer GCN: out = ReLU(Â(ReLU(Â(Â (X W1^T) +b1) W2^T +b2)) W3^T) +b3
// Â = D^{-1/2}(A+I)D^{-1/2}, deg = in-degree + 1 (self loop).
//
// R22: RESTORE R17-exact (best measured: 376.2us). R21 pm: (a) random
// global-atomic degree histogram = 66us (same random-line wall as the
// gathers); (b) co-dispatch fusion measured NEGATIVE (~-29us: block-order
// dispatch defeats overlap, phases contend). Both abandoned.
// Session landscape: aggregates at the random-gather delivery wall
// (3 request profiles within 5%; fetch -10% -> time -1.6%); GEMMs at a
// robust ~45-48us floor across 5 structures with all pipes <16%;
// overlap attempts regress. This config is the measured optimum.
// ---------------------------------------------------------------------------

#define NPB 256          // nodes per bucket (bucket = dst >> 8)
#define CAP 4672         // edges capacity per bucket region
#define BIN_WGS 512      // workgroups in bin_edges

typedef short bfrag __attribute__((ext_vector_type(8)));       // 8 bf16
typedef float f32x4 __attribute__((ext_vector_type(4)));
typedef unsigned short u16x8 __attribute__((ext_vector_type(8)));

__global__ __launch_bounds__(256) void bin_edges(const int* __restrict__ src,
                                                 const int* __restrict__ dst,
                                                 int* __restrict__ cur,
                                                 int* __restrict__ binned,
                                                 int E, int B) {
  __shared__ int lc[512];
  __shared__ int lbase[512];
  const int t = threadIdx.x;
  const int chunk = (E + BIN_WGS - 1) / BIN_WGS;
  const int e0 = blockIdx.x * chunk;
  const int e1 = min(E, e0 + chunk);

  for (int i = t; i < B; i += 256) lc[i] = 0;
  __syncthreads();
  for (int e = e0 + t; e < e1; e += 256) {
    int d = dst[e];
    atomicAdd(&lc[d >> 8], 1);
  }
  __syncthreads();
  for (int i = t; i < B; i += 256) {
    int c = lc[i];
    lbase[i] = c ? atomicAdd(&cur[i], c) : 0;
    lc[i] = 0;
  }
  __syncthreads();
  for (int e = e0 + t; e < e1; e += 256) {
    int d = dst[e];
    int s = __builtin_nontemporal_load(&src[e]);
    int bk = d >> 8;
    int p = lbase[bk] + atomicAdd(&lc[bk], 1);
    if (p < (bk + 1) * CAP)
      binned[p] = ((d & 255) << 24) | s;
  }
}

__global__ __launch_bounds__(256) void build_buckets(const int* __restrict__ binned,
                                                     const int* __restrict__ cur,
                                                     int* __restrict__ cols,
                                                     int2* __restrict__ off2,
                                                     float* __restrict__ dinv,
                                                     int N) {
  __shared__ int eb[CAP];
  __shared__ int ob[CAP];
  __shared__ int lc[256];
  __shared__ int sc[256];
  const int b = blockIdx.x;
  const int t = threadIdx.x;
  const int base = b * CAP;
  const int cntb = min(cur[b] - base, CAP);

  for (int i = t; i < cntb; i += 256) eb[i] = binned[base + i];
  lc[t] = 0;
  __syncthreads();
  for (int i = t; i < cntb; i += 256)
    atomicAdd(&lc[(unsigned)eb[i] >> 24], 1);
  __syncthreads();
  int myc = lc[t];
  sc[t] = myc;
  __syncthreads();
  for (int d = 1; d < 256; d <<= 1) {
    int a = (t >= d) ? sc[t - d] : 0;
    __syncthreads();
    sc[t] += a;
    __syncthreads();
  }
  int excl = sc[t] - myc;
  int node = b * NPB + t;
  if (node < N) {
    off2[node] = make_int2(base + excl, base + excl + myc);
    dinv[node] = rsqrtf((float)(myc + 1));
  }
  lc[t] = excl;
  __syncthreads();
  for (int i = t; i < cntb; i += 256) {
    int e = eb[i];
    int p = atomicAdd(&lc[(unsigned)e >> 24], 1);
    ob[p] = e & 0xFFFFFF;
  }
  __syncthreads();
  for (int i = t; i < cntb; i += 256) cols[base + i] = ob[i];
}

// ---------------------------------------------------------------------------
__device__ inline unsigned short bf16rne(float x) {
  unsigned u = __float_as_uint(x);
  return (unsigned short)((u + 0x7FFFu + ((u >> 16) & 1u)) >> 16);
}
__device__ inline float bf16lo(unsigned q) { return __uint_as_float(q << 16); }
__device__ inline float bf16hi(unsigned q) { return __uint_as_float(q & 0xFFFF0000u); }

// All three W -> hi/lo bf16 plane splits + cur init in ONE launch
__global__ __launch_bounds__(256) void split_w3(const float* __restrict__ W1,
                                                const float* __restrict__ W2,
                                                const float* __restrict__ W3,
                                                unsigned short* __restrict__ w1h,
                                                unsigned short* __restrict__ w1l,
                                                unsigned short* __restrict__ w2h,
                                                unsigned short* __restrict__ w2l,
                                                unsigned short* __restrict__ w3h,
                                                unsigned short* __restrict__ w3l,
                                                int* __restrict__ cur, int B) {
  int i = blockIdx.x * 256 + threadIdx.x;
  const float* W;
  unsigned short *hi, *lo;
  int j;
  if (i < 16384) {
    W = W1; hi = w1h; lo = w1l; j = i;
  } else if (i < 32768) {
    W = W2; hi = w2h; lo = w2l; j = i - 16384;
  } else if (i < 40960) {
    W = W3; hi = w3h; lo = w3l; j = i - 32768;
  } else if (i < 40960 + B) {
    cur[i - 40960] = (i - 40960) * CAP;
    return;
  } else {
    return;
  }
  float v = W[j];
  unsigned short h = bf16rne(v);
  hi[j] = h;
  lo[j] = bf16rne(v - __uint_as_float((unsigned)h << 16));
}

// ---------------------------------------------------------------------------
// GEMM: Y[m][c] = bf16( dinv[m] * dot(X[m][:], W[c][:]) ), K=128.
// One block per 64-row m-tile; loops over cc chunks of 64 W rows. A frags
// loaded once into regs; W tile restaged per chunk from L2 (~free).
// CSOUT: write half-row-major layout Y[(c2*M + row)*64 + t*16 + col_l]
// (cg == c2: channels c2*64..c2*64+63 form one contiguous 128B half-row).
// ---------------------------------------------------------------------------
#define LDP 136  // padded LDS row stride (bf16): breaks 16-way bank conflict

// Layer 2/3 variant: A from bf16 hi/lo planes in global.
template <int OUTC, bool CSOUT>
__global__ __launch_bounds__(256) void gemm_planes(const unsigned short* __restrict__ Xh,
                                                   const unsigned short* __restrict__ Xl,
                                                   const unsigned short* __restrict__ Whg,
                                                   const unsigned short* __restrict__ Wlg,
                                                   const float* __restrict__ dinv,
                                                   unsigned short* __restrict__ Y,
                                                   int M) {
  constexpr int CHUNKS = OUTC / 64;
  __shared__ unsigned short Whi[64 * LDP], Wlo[64 * LDP];
  const int tid = threadIdx.x;
  const int m_base = blockIdx.x * 64;
  const int lane = tid & 63;
  const int wv = tid >> 6;
  const int col_l = lane & 15;   // A-row within wave tile / D col
  const int quad = lane >> 4;    // k-quad / D row group
  const size_t arow = (size_t)min(m_base + wv * 16 + col_l, M - 1) * 128;
  const int bBase = col_l * LDP + quad * 8;

  bfrag aH[4], aL[4];
#pragma unroll
  for (int ks = 0; ks < 4; ++ks) {
    aH[ks] = *(const bfrag*)(Xh + arow + ks * 32 + quad * 8);
    aL[ks] = *(const bfrag*)(Xl + arow + ks * 32 + quad * 8);
  }

  f32x4 acc[CHUNKS][4];
#pragma unroll
  for (int c2 = 0; c2 < CHUNKS; ++c2)
#pragma unroll
    for (int t = 0; t < 4; ++t) acc[c2][t] = {0.f, 0.f, 0.f, 0.f};

#pragma unroll
  for (int c2 = 0; c2 < CHUNKS; ++c2) {
    if (c2) __syncthreads();  // all reads of previous W tile done
    for (int idx = tid; idx < 64 * 16; idx += 256) {
      int r = idx >> 4, g = idx & 15;
      *(u16x8*)(Whi + r * LDP + g * 8) =
          *(const u16x8*)(Whg + (size_t)(c2 * 64 + r) * 128 + g * 8);
      *(u16x8*)(Wlo + r * LDP + g * 8) =
          *(const u16x8*)(Wlg + (size_t)(c2 * 64 + r) * 128 + g * 8);
    }
    __syncthreads();
#pragma unroll
    for (int ks = 0; ks < 4; ++ks) {
#pragma unroll
      for (int t = 0; t < 4; ++t) {
        int bo = bBase + t * 16 * LDP + ks * 32;
        bfrag bHi = *(const bfrag*)(Whi + bo);
        bfrag bLo = *(const bfrag*)(Wlo + bo);
        acc[c2][t] = __builtin_amdgcn_mfma_f32_16x16x32_bf16(aH[ks], bHi, acc[c2][t], 0, 0, 0);
        acc[c2][t] = __builtin_amdgcn_mfma_f32_16x16x32_bf16(aL[ks], bHi, acc[c2][t], 0, 0, 0);
        acc[c2][t] = __builtin_amdgcn_mfma_f32_16x16x32_bf16(aH[ks], bLo, acc[c2][t], 0, 0, 0);
      }
    }
  }

#pragma unroll
  for (int r = 0; r < 4; ++r) {
    int row = m_base + wv * 16 + quad * 4 + r;
    if (row < M) {
      float s = dinv[row];
#pragma unroll
      for (int c2 = 0; c2 < CHUNKS; ++c2)
#pragma unroll
        for (int t = 0; t < 4; ++t) {
          unsigned short h = bf16rne(acc[c2][t][r] * s);
          if (CSOUT)
            Y[((size_t)c2 * M + row) * 64 + t * 16 + col_l] = h;
          else
            Y[(size_t)row * OUTC + c2 * 64 + t * 16 + col_l] = h;
        }
    }
  }
}

// Layer-1 variant: A from f32 X, split to hi/lo bf16 in-register.
template <int OUTC, bool CSOUT>
__global__ __launch_bounds__(256) void gemm_xsplit(const float* __restrict__ X,
                                                   const unsigned short* __restrict__ Whg,
                                                   const unsigned short* __restrict__ Wlg,
                                                   const float* __restrict__ dinv,
                                                   unsigned short* __restrict__ Y,
                                                   int M) {
  constexpr int CHUNKS = OUTC / 64;
  __shared__ unsigned short Whi[64 * LDP], Wlo[64 * LDP];
  const int tid = threadIdx.x;
  const int m_base = blockIdx.x * 64;
  const int lane = tid & 63;
  const int wv = tid >> 6;
  const int col_l = lane & 15;
  const int quad = lane >> 4;
  const size_t arow = (size_t)min(m_base + wv * 16 + col_l, M - 1) * 128;
  const int bBase = col_l * LDP + quad * 8;

  bfrag aH[4], aL[4];
#pragma unroll
  for (int ks = 0; ks < 4; ++ks) {
    float4 v0 = *(const float4*)(X + arow + ks * 32 + quad * 8);
    float4 v1 = *(const float4*)(X + arow + ks * 32 + quad * 8 + 4);
    float vv[8] = {v0.x, v0.y, v0.z, v0.w, v1.x, v1.y, v1.z, v1.w};
#pragma unroll
    for (int j = 0; j < 8; ++j) {
      unsigned short h = bf16rne(vv[j]);
      aH[ks][j] = (short)h;
      aL[ks][j] = (short)bf16rne(vv[j] - __uint_as_float((unsigned)h << 16));
    }
  }

  f32x4 acc[CHUNKS][4];
#pragma unroll
  for (int c2 = 0; c2 < CHUNKS; ++c2)
#pragma unroll
    for (int t = 0; t < 4; ++t) acc[c2][t] = {0.f, 0.f, 0.f, 0.f};

#pragma unroll
  for (int c2 = 0; c2 < CHUNKS; ++c2) {
    if (c2) __syncthreads();
    for (int idx = tid; idx < 64 * 16; idx += 256) {
      int r = idx >> 4, g = idx & 15;
      *(u16x8*)(Whi + r * LDP + g * 8) =
          *(const u16x8*)(Whg + (size_t)(c2 * 64 + r) * 128 + g * 8);
      *(u16x8*)(Wlo + r * LDP + g * 8) =
          *(const u16x8*)(Wlg + (size_t)(c2 * 64 + r) * 128 + g * 8);
    }
    __syncthreads();
#pragma unroll
    for (int ks = 0; ks < 4; ++ks) {
#pragma unroll
      for (int t = 0; t < 4; ++t) {
        int bo = bBase + t * 16 * LDP + ks * 32;
        bfrag bHi = *(const bfrag*)(Whi + bo);
        bfrag bLo = *(const bfrag*)(Wlo + bo);
        acc[c2][t] = __builtin_amdgcn_mfma_f32_16x16x32_bf16(aH[ks], bHi, acc[c2][t], 0, 0, 0);
        acc[c2][t] = __builtin_amdgcn_mfma_f32_16x16x32_bf16(aL[ks], bHi, acc[c2][t], 0, 0, 0);
        acc[c2][t] = __builtin_amdgcn_mfma_f32_16x16x32_bf16(aH[ks], bLo, acc[c2][t], 0, 0, 0);
      }
    }
  }

#pragma unroll
  for (int r = 0; r < 4; ++r) {
    int row = m_base + wv * 16 + quad * 4 + r;
    if (row < M) {
      float s = dinv[row];
#pragma unroll
      for (int c2 = 0; c2 < CHUNKS; ++c2)
#pragma unroll
        for (int t = 0; t < 4; ++t) {
          unsigned short h = bf16rne(acc[c2][t][r] * s);
          if (CSOUT)
            Y[((size_t)c2 * M + row) * 64 + t * 16 + col_l] = h;
          else
            Y[(size_t)row * OUTC + c2 * 64 + t * 16 + col_l] = h;
        }
    }
  }
}

__device__ inline void acc_add(float* a, uint4 d) {
  a[0] += bf16lo(d.x); a[1] += bf16hi(d.x);
  a[2] += bf16lo(d.y); a[3] += bf16hi(d.y);
  a[4] += bf16lo(d.z); a[5] += bf16hi(d.z);
  a[6] += bf16lo(d.w); a[7] += bf16hi(d.w);
}

// ---------------------------------------------------------------------------
// Aggregate v8 (C=128, cg=2 half-row split): block handles half cg = bid&1;
// under round-robin block->XCD dispatch each XCD's parity is fixed -> reads
// only xs2[cg] = contiguous [N][64ch] 12.8MB slice. 8 lanes/node gather one
// FULL 128B line per edge (v4's request profile). 8-edge chunks, 4 deep,
// ascending order. Output: standard [N][128] hi/lo planes.
// ---------------------------------------------------------------------------
__global__ __launch_bounds__(256) void aggregate_h2(const unsigned short* __restrict__ xs,
                                                    const int2* __restrict__ off2,
                                                    const int* __restrict__ cols,
                                                    const float* __restrict__ dinv,
                                                    const float* __restrict__ bias,
                                                    unsigned short* __restrict__ oh,
                                                    unsigned short* __restrict__ ol,
                                                    int N) {
  const int cg = blockIdx.x & 1;        // half-row group; fixed per XCD parity
  const int tile = blockIdx.x >> 1;
  const int t = threadIdx.x;
  const int gl = t & 7;                 // lane within node (8 x 16B = 128B)
  const int node = tile * 32 + (t >> 3);
  if (node >= N) return;

  const char* xb = (const char*)xs + (size_t)cg * N * 128;  // contiguous slice
  const unsigned go = (unsigned)gl * 16;

  float acc[8];
  {
    // self-loop row (pre-scaled by dinv[node] in the GEMM epilogue)
    uint4 d = *(const uint4*)(xb + (size_t)node * 128 + go);
    acc[0] = bf16lo(d.x); acc[1] = bf16hi(d.x);
    acc[2] = bf16lo(d.y); acc[3] = bf16hi(d.y);
    acc[4] = bf16lo(d.z); acc[5] = bf16hi(d.z);
    acc[6] = bf16lo(d.w); acc[7] = bf16hi(d.w);
  }

  const int2 oo = off2[node];
  const int en = oo.y;
  for (int e0 = oo.x; e0 < en; e0 += 8) {
    int col = __builtin_nontemporal_load(&cols[min(e0 + gl, en - 1)]);
    int m = en - e0;
    if (m > 8) m = 8;
    const int c1 = m - 1;
    for (int j = 0; j < m; j += 4) {
      int s0 = __shfl(col, min(j,     c1), 8);
      int s1 = __shfl(col, min(j + 1, c1), 8);
      int s2 = __shfl(col, min(j + 2, c1), 8);
      int s3 = __shfl(col, min(j + 3, c1), 8);
      uint4 d0 = *(const uint4*)(xb + (size_t)s0 * 128 + go);
      uint4 d1 = *(const uint4*)(xb + (size_t)s1 * 128 + go);
      uint4 d2 = *(const uint4*)(xb + (size_t)s2 * 128 + go);
      uint4 d3 = *(const uint4*)(xb + (size_t)s3 * 128 + go);
      acc_add(acc, d0);                       // j < m always
      if (j + 1 < m) acc_add(acc, d1);
      if (j + 2 < m) acc_add(acc, d2);
      if (j + 3 < m) acc_add(acc, d3);
    }
  }

  const float dd = dinv[node];
  const float4 bA = *(const float4*)(bias + cg * 64 + gl * 8);
  const float4 bB = *(const float4*)(bias + cg * 64 + gl * 8 + 4);
  float h[8];
  h[0] = acc[0] * dd + bA.x; h[1] = acc[1] * dd + bA.y;
  h[2] = acc[2] * dd + bA.z; h[3] = acc[3] * dd + bA.w;
  h[4] = acc[4] * dd + bB.x; h[5] = acc[5] * dd + bB.y;
  h[6] = acc[6] * dd + bB.z; h[7] = acc[7] * dd + bB.w;
#pragma unroll
  for (int q = 0; q < 8; ++q) h[q] = fmaxf(h[q], 0.f);

  u16x8 hv, lv;
#pragma unroll
  for (int q = 0; q < 8; ++q) {
    unsigned short hb = bf16rne(h[q]);
    hv[q] = hb;
    lv[q] = bf16rne(h[q] - __uint_as_float((unsigned)hb << 16));
  }
  const size_t ob = (size_t)node * 128 + cg * 64 + gl * 8;
  __builtin_nontemporal_store(hv, (u16x8*)(oh + ob));
  __builtin_nontemporal_store(lv, (u16x8*)(ol + ob));
}

// ---------------------------------------------------------------------------
// Aggregate v4 (kept for the C=64 final layer; standard [N][64] xs layout).
// ---------------------------------------------------------------------------
template <int C, bool RELU, bool SPLIT>
__global__ __launch_bounds__(256) void aggregate4(const unsigned short* __restrict__ xs,
                                                  const int2* __restrict__ off2,
                                                  const int* __restrict__ cols,
                                                  const float* __restrict__ dinv,
                                                  const float* __restrict__ bias,
                                                  float* __restrict__ outf,
                                                  unsigned short* __restrict__ oh,
                                                  unsigned short* __restrict__ ol,
                                                  int N) {
  constexpr int GL = C / 8;            // lanes per node
  constexpr int LSH = (GL == 16) ? 4 : 3;
  constexpr int NPBk = 256 / GL;       // nodes per block
  const int t = threadIdx.x;
  const int gl = t & (GL - 1);
  const int node = blockIdx.x * NPBk + (t >> LSH);
  if (node >= N) return;

  const unsigned co = (unsigned)gl * 16;  // byte offset of this lane's 8 ch
  const char* xb = (const char*)xs;

  float acc[8];
  {
    uint4 d = *(const uint4*)(xb + (size_t)node * (C * 2) + co);
    acc[0] = bf16lo(d.x); acc[1] = bf16hi(d.x);
    acc[2] = bf16lo(d.y); acc[3] = bf16hi(d.y);
    acc[4] = bf16lo(d.z); acc[5] = bf16hi(d.z);
    acc[6] = bf16lo(d.w); acc[7] = bf16hi(d.w);
  }

  const int2 oo = off2[node];
  const int en = oo.y;
  for (int e0 = oo.x; e0 < en; e0 += GL) {
    int col = __builtin_nontemporal_load(&cols[min(e0 + gl, en - 1)]);
    int m = en - e0;
    if (m > GL) m = GL;
    const int c1 = m - 1;
    for (int j = 0; j < m; j += 4) {
      int s0 = __shfl(col, min(j,     c1), GL);
      int s1 = __shfl(col, min(j + 1, c1), GL);
      int s2 = __shfl(col, min(j + 2, c1), GL);
      int s3 = __shfl(col, min(j + 3, c1), GL);
      uint4 d0 = *(const uint4*)(xb + (size_t)s0 * (C * 2) + co);
      uint4 d1 = *(const uint4*)(xb + (size_t)s1 * (C * 2) + co);
      uint4 d2 = *(const uint4*)(xb + (size_t)s2 * (C * 2) + co);
      uint4 d3 = *(const uint4*)(xb + (size_t)s3 * (C * 2) + co);
      acc_add(acc, d0);                       // j < m always
      if (j + 1 < m) acc_add(acc, d1);
      if (j + 2 < m) acc_add(acc, d2);
      if (j + 3 < m) acc_add(acc, d3);
    }
  }

  const float dd = dinv[node];
  const float4 bA = *(const float4*)(bias + gl * 8);
  const float4 bB = *(const float4*)(bias + gl * 8 + 4);
  float h[8];
  h[0] = acc[0] * dd + bA.x; h[1] = acc[1] * dd + bA.y;
  h[2] = acc[2] * dd + bA.z; h[3] = acc[3] * dd + bA.w;
  h[4] = acc[4] * dd + bB.x; h[5] = acc[5] * dd + bB.y;
  h[6] = acc[6] * dd + bB.z; h[7] = acc[7] * dd + bB.w;
  if (RELU) {
#pragma unroll
    for (int q = 0; q < 8; ++q) h[q] = fmaxf(h[q], 0.f);
  }
  if (SPLIT) {
    u16x8 hv, lv;
#pragma unroll
    for (int q = 0; q < 8; ++q) {
      unsigned short hb = bf16rne(h[q]);
      hv[q] = hb;
      lv[q] = bf16rne(h[q] - __uint_as_float((unsigned)hb << 16));
    }
    __builtin_nontemporal_store(hv, (u16x8*)(oh + (size_t)node * C + gl * 8));
    __builtin_nontemporal_store(lv, (u16x8*)(ol + (size_t)node * C + gl * 8));
  } else {
    f32x4 oA = {h[0], h[1], h[2], h[3]};
    f32x4 oB = {h[4], h[5], h[6], h[7]};
    __builtin_nontemporal_store(oA, (f32x4*)(outf + (size_t)node * C + gl * 8));
    __builtin_nontemporal_store(oB, (f32x4*)(outf + (size_t)node * C + gl * 8 + 4));
  }
}

// ---------------------------------------------------------------------------

extern "C" void kernel_launch(void* const* d_in, const int* in_sizes, int n_in,
                              void* d_out, int out_size, void* d_ws, size_t ws_size,
                              hipStream_t stream) {
  const float* x  = (const float*)d_in[0];
  const int*   ei = (const int*)d_in[1];
  const float* W1 = (const float*)d_in[2];
  const float* b1 = (const float*)d_in[3];
  const float* W2 = (const float*)d_in[4];
  const float* b2 = (const float*)d_in[5];
  const float* W3 = (const float*)d_in[6];
  const float* b3 = (const float*)d_in[7];

  const int N = in_sizes[0] / 128;
  const int E = in_sizes[1] / 2;
  const int* src = ei;
  const int* dst = ei + E;
  const int B = (N + NPB - 1) / NPB;

  char* w = (char*)d_ws;
  size_t p = 0;
  auto alloc = [&](size_t bytes) -> void* {
    void* r = w + p;
    p = (p + bytes + 255) & ~(size_t)255;
    return r;
  };
  float*    dinv   = (float*)alloc((size_t)N * 4);
  int2*     off2   = (int2*)alloc((size_t)N * 8);
  int*      cur    = (int*)alloc((size_t)B * 4);
  int*      binned = (int*)alloc((size_t)B * CAP * 4);
  int*      cols   = (int*)alloc((size_t)B * CAP * 4);
  unsigned short* xsb = (unsigned short*)alloc((size_t)N * 128 * 2);  // GEMM out
  unsigned short* hh  = (unsigned short*)alloc((size_t)N * 128 * 2);  // h hi plane
  unsigned short* hl  = (unsigned short*)alloc((size_t)N * 128 * 2);  // h lo plane
  unsigned short* w1h = (unsigned short*)alloc(128 * 128 * 2);
  unsigned short* w1l = (unsigned short*)alloc(128 * 128 * 2);
  unsigned short* w2h = (unsigned short*)alloc(128 * 128 * 2);
  unsigned short* w2l = (unsigned short*)alloc(128 * 128 * 2);
  unsigned short* w3h = (unsigned short*)alloc(64 * 128 * 2);
  unsigned short* w3l = (unsigned short*)alloc(64 * 128 * 2);

  split_w3<<<(40960 + B + 255) / 256, 256, 0, stream>>>(W1, W2, W3, w1h, w1l,
                                                        w2h, w2l, w3h, w3l,
                                                        cur, B);
  bin_edges<<<BIN_WGS, 256, 0, stream>>>(src, dst, cur, binned, E, B);
  build_buckets<<<B, 256, 0, stream>>>(binned, cur, cols, off2, dinv, N);

  const int gb = (N + 63) / 64;
  const int ah2 = ((N + 31) / 32) * 2;  // half-row split: 2 cgs per node tile
  const int ab64 = (N + 31) / 32;       // 32 nodes per block (C=64)

  gemm_xsplit<128, true><<<gb, 256, 0, stream>>>(x, w1h, w1l, dinv, xsb, N);
  aggregate_h2<<<ah2, 256, 0, stream>>>(xsb, off2, cols, dinv, b1, hh, hl, N);
  gemm_planes<128, true><<<gb, 256, 0, stream>>>(hh, hl, w2h, w2l, dinv, xsb, N);
  aggregate_h2<<<ah2, 256, 0, stream>>>(xsb, off2, cols, dinv, b2, hh, hl, N);
  gemm_planes<64, false><<<gb, 256, 0, stream>>>(hh, hl, w3h, w3l, dinv, xsb, N);
  aggregate4<64, false, false><<<ab64, 256, 0, stream>>>(xsb, off2, cols, dinv, b3,
                                                         (float*)d_out, nullptr,
                                                         nullptr, N);
}